// Round 4
// baseline (1096.695 us; speedup 1.0000x reference)
//
#include <hip/hip_runtime.h>
#include <cstdint>
#include <cstddef>

// EncoderLayer (Autoformer auto-correlation) on gfx950. fp32 I/O, bf16 MFMA.
// R4: reinstated global_load_lds width-16 staging (m97 pattern) in the GEMM
// core. R1's NaN was the fp32-read-as-bf16 dtype bug, NOT the async staging
// (lane->LDS mapping re-audited: lane i -> base+16i == row(i>>2), col 16(i&3),
// exactly the row-major 64B-row layout the fragment reads expect).
//
// Key identity: mean over channels of irfft(rfft(q)*conj(rfft(k))) ==
//   (1/D) * wrap-diagonal sums of the per-batch gram matrix q @ k^T.

typedef unsigned short u16;
typedef unsigned int   u32;
typedef __bf16  bf16x8 __attribute__((ext_vector_type(8)));
typedef float   f32x4  __attribute__((ext_vector_type(4)));

#define BB 8
#define LL 2048
#define DD 1024
#define FF 4096
#define NT 16384   // B*L
#define NCAND 16
#define NTOP 7

static __device__ __forceinline__ float b2f(u16 u) {
  union { u32 i; float f; } x; x.i = ((u32)u) << 16; return x.f;
}
static __device__ __forceinline__ u16 f2b(float f) {
  union { float f; u32 i; } x; x.f = f;
  u32 r = (x.i + 0x7fffu + ((x.i >> 16) & 1u)) >> 16;  // RNE
  return (u16)r;
}
static __device__ __forceinline__ u32 pk2(float a, float b) {
  return (u32)f2b(a) | ((u32)f2b(b) << 16);
}

// async global->LDS, 16B per lane; LDS dest = wave-uniform base + lane*16
#define GLD_LDS16(gp, lp) __builtin_amdgcn_global_load_lds( \
    (const __attribute__((address_space(1))) u32*)(void*)(gp), \
    (__attribute__((address_space(3))) u32*)(void*)(lp), 16, 0, 0)

// ---------------------------------------------------------------- GEMM core
// C(MxN) = A(MxK) @ Bt(NxK)^T, bf16 in, fp32 accum. 128x128 tile, BK=32,
// 256 threads = 4 waves, each wave 64x64 via 4x4 of mfma_f32_16x16x32_bf16.
// Staging: global_load_lds dwordx4 — waves 0/1 stage A rows 0-63/64-127,
// waves 2/3 stage B; 4 issues per wave per K-step (16 rows x 1KiB each).
__device__ __forceinline__ void gemm_tile(
    const u16* __restrict__ A, const u16* __restrict__ Bt,
    int lda, int ldb, int K, u16* As, u16* Bs, f32x4 acc[4][4])
{
  const int tid  = threadIdx.x;
  const int w    = tid >> 6;
  const int lane = tid & 63;
  const bool isA = (w < 2);
  const u16* G   = isA ? A : Bt;
  const int ldg  = isA ? lda : ldb;
  u16* S         = isA ? As : Bs;
  const int rbase = (w & 1) * 64;            // 64-row staging slice per wave
  const int srow  = rbase + (lane >> 2);
  const int scol  = (lane & 3) * 8;
  const int wm = (w >> 1) * 64;              // wave tile origin
  const int wn = (w & 1) * 64;
  const int fm = lane & 15;                  // A/B fragment row (m or n)
  const int fk = (lane >> 4) * 8;            // fragment k offset
  const u16* gbase = G + (size_t)srow * ldg + scol;

  for (int kk = 0; kk < K; kk += 32) {
#pragma unroll
    for (int j = 0; j < 4; ++j) {
      GLD_LDS16(gbase + (size_t)(j * 16) * ldg + kk,
                S + (rbase + j * 16) * 32);
    }
    __syncthreads();   // drains vmcnt -> LDS tiles ready
    bf16x8 af[4], bfv[4];
#pragma unroll
    for (int i = 0; i < 4; ++i)
      af[i] = *(const bf16x8*)(As + (wm + i * 16 + fm) * 32 + fk);
#pragma unroll
    for (int j = 0; j < 4; ++j)
      bfv[j] = *(const bf16x8*)(Bs + (wn + j * 16 + fm) * 32 + fk);
#pragma unroll
    for (int i = 0; i < 4; ++i)
#pragma unroll
      for (int j = 0; j < 4; ++j)
        acc[i][j] = __builtin_amdgcn_mfma_f32_16x16x32_bf16(af[i], bfv[j], acc[i][j], 0, 0, 0);
    __syncthreads();   // LDS readers done before next iter's DMA writes
  }
}

// C = A@Bt^T + bias(fp32), optional relu; optional bf16 "lo" residual store
// for rows < lo_rows (double-bf16 split used by the refine kernel).
__global__ __launch_bounds__(256, 2)
void gemm_bias_k(const u16* __restrict__ A, const u16* __restrict__ Bt,
                 const float* __restrict__ bias, u16* __restrict__ C,
                 u16* __restrict__ Clo, int M, int N, int K,
                 int lda, int ldb, int ldc, int relu, int lo_rows)
{
  __shared__ u16 As[128 * 32];
  __shared__ u16 Bs[128 * 32];
  f32x4 acc[4][4];
#pragma unroll
  for (int i = 0; i < 4; ++i)
#pragma unroll
    for (int j = 0; j < 4; ++j)
#pragma unroll
      for (int r = 0; r < 4; ++r) acc[i][j][r] = 0.f;

  const int bm = blockIdx.y * 128, bn = blockIdx.x * 128;
  gemm_tile(A + (size_t)bm * lda, Bt + (size_t)bn * ldb, lda, ldb, K, As, Bs, acc);

  const int tid = threadIdx.x, w = tid >> 6, lane = tid & 63;
  const int wm = (w >> 1) * 64, wn = (w & 1) * 64;
  const int crow = (lane >> 4) * 4, ccol = lane & 15;
  float bvs[4];
#pragma unroll
  for (int j = 0; j < 4; ++j) bvs[j] = bias[bn + wn + j * 16 + ccol];
#pragma unroll
  for (int i = 0; i < 4; ++i) {
#pragma unroll
    for (int r = 0; r < 4; ++r) {
      const int row = bm + wm + i * 16 + crow + r;
      const size_t rowoff = (size_t)row * ldc;
#pragma unroll
      for (int j = 0; j < 4; ++j) {
        float val = acc[i][j][r] + bvs[j];
        if (relu) val = fmaxf(val, 0.f);
        const int col = bn + wn + j * 16 + ccol;
        const u16 hb = f2b(val);
        C[rowoff + col] = hb;
        if (Clo != nullptr && row < lo_rows)
          Clo[rowoff + col] = f2b(val - b2f(hb));
      }
    }
  }
}

// Gram GEMM with fused wrap-diagonal reduction:
// r[b,l] += sum over tile elems of q[t,:]*k[s,:] where (t-s) mod L == l
__global__ __launch_bounds__(256, 2)
void gram_k(const u16* __restrict__ q, const u16* __restrict__ kmat,
            float* __restrict__ rout)
{
  __shared__ u16 As[128 * 32];
  __shared__ u16 Bs[128 * 32];
  __shared__ float diag[255];
  const int b = blockIdx.z;
  const int bm = blockIdx.y * 128, bn = blockIdx.x * 128;
  for (int idx = threadIdx.x; idx < 255; idx += 256) diag[idx] = 0.f;

  f32x4 acc[4][4];
#pragma unroll
  for (int i = 0; i < 4; ++i)
#pragma unroll
    for (int j = 0; j < 4; ++j)
#pragma unroll
      for (int r = 0; r < 4; ++r) acc[i][j][r] = 0.f;

  const u16* A  = q    + (size_t)b * LL * DD + (size_t)bm * DD;
  const u16* Bt = kmat + (size_t)b * LL * DD + (size_t)bn * DD;
  gemm_tile(A, Bt, DD, DD, DD, As, Bs, acc);

  __syncthreads();   // diag[] zero-init visible; LDS readers done
  const int tid = threadIdx.x, w = tid >> 6, lane = tid & 63;
  const int wm = (w >> 1) * 64, wn = (w & 1) * 64;
  const int crow = (lane >> 4) * 4, ccol = lane & 15;
  const int dbase = wm - wn + crow - ccol + 127;
#pragma unroll
  for (int d = -3; d <= 3; ++d) {
#pragma unroll
    for (int r = 0; r < 4; ++r) {
      float s = 0.f;
#pragma unroll
      for (int i = 0; i < 4; ++i) {
        const int j = i - d;
        if (0 <= j && j < 4) s += acc[i][j][r];
      }
      atomicAdd(&diag[dbase + d * 16 + r], s);
    }
  }
  __syncthreads();
  for (int idx = threadIdx.x; idx < 255; idx += 256) {
    const int l = ((bm - bn + idx - 127) + 4096) & (LL - 1);
    atomicAdd(&rout[b * LL + l], diag[idx]);
  }
}

// ----------------------------------------------------------- small kernels
__global__ void zero_k(float* p, int n) {
  int i = blockIdx.x * 256 + threadIdx.x;
  if (i < n) p[i] = 0.f;
}

// fp32 -> bf16, 8 elements per thread
__global__ void convert_k(const float* __restrict__ in, u16* __restrict__ out,
                          int n8)
{
  const int i = blockIdx.x * 256 + threadIdx.x;
  if (i >= n8) return;
  const float4 f0 = *(const float4*)(in + (size_t)i * 8);
  const float4 f1 = *(const float4*)(in + (size_t)i * 8 + 4);
  uint4 o;
  o.x = pk2(f0.x, f0.y); o.y = pk2(f0.z, f0.w);
  o.z = pk2(f1.x, f1.y); o.w = pk2(f1.z, f1.w);
  *(uint4*)(out + (size_t)i * 8) = o;
}

// fp32 in (R x C) -> bf16 transposed out (C x R)
__global__ void transpose_k(const float* __restrict__ in, u16* __restrict__ out,
                            int R, int C)
{
  __shared__ float tile[32][33];
  const int bx = blockIdx.x * 32;  // col base
  const int by = blockIdx.y * 32;  // row base
  const int tx = threadIdx.x, ty = threadIdx.y;
#pragma unroll
  for (int i = 0; i < 32; i += 8)
    tile[ty + i][tx] = in[(size_t)(by + ty + i) * C + bx + tx];
  __syncthreads();
#pragma unroll
  for (int i = 0; i < 32; i += 8)
    out[(size_t)(bx + ty + i) * R + by + tx] = f2b(tile[tx][ty + i]);
}

// per-batch iterative top-16 argmax (stable: ties -> lower index, like lax.top_k)
__global__ void topk16_k(const float* __restrict__ r, float* __restrict__ cand_val,
                         int* __restrict__ cand_idx)
{
  const int b = blockIdx.x;
  __shared__ float vals[LL];
  __shared__ float bvv[256];
  __shared__ int   bii[256];
  for (int i = threadIdx.x; i < LL; i += 256) vals[i] = r[b * LL + i] * (1.f / 1024.f);
  __syncthreads();
  for (int it = 0; it < NCAND; ++it) {
    float best = -1e30f; int bidx = 0;
    for (int i = threadIdx.x; i < LL; i += 256) {
      float v = vals[i];
      if (v > best) { best = v; bidx = i; }
    }
    bvv[threadIdx.x] = best; bii[threadIdx.x] = bidx;
    __syncthreads();
    for (int s = 128; s > 0; s >>= 1) {
      if ((int)threadIdx.x < s) {
        float ov = bvv[threadIdx.x + s]; int oi = bii[threadIdx.x + s];
        if (ov > bvv[threadIdx.x] ||
            (ov == bvv[threadIdx.x] && oi < bii[threadIdx.x])) {
          bvv[threadIdx.x] = ov; bii[threadIdx.x] = oi;
        }
      }
      __syncthreads();
    }
    if (threadIdx.x == 0) {
      cand_val[b * NCAND + it] = bvv[0];
      cand_idx[b * NCAND + it] = bii[0];
      vals[bii[0]] = -1e30f;
    }
    __syncthreads();
  }
}

// high-precision rescore of batch-0's 16 candidate lags using hi+lo splits
__global__ void refine_k(const u16* __restrict__ qh, const u16* __restrict__ ql,
                         const u16* __restrict__ kh, const u16* __restrict__ kl,
                         const int* __restrict__ ci, float* __restrict__ refined)
{
  __shared__ int lag[NCAND];
  __shared__ float part[NCAND];
  if (threadIdx.x < NCAND) { lag[threadIdx.x] = ci[threadIdx.x]; part[threadIdx.x] = 0.f; }
  __syncthreads();
  const int c = threadIdx.x * 4;
  float p[NCAND];
#pragma unroll
  for (int i = 0; i < NCAND; ++i) p[i] = 0.f;
  const int t0 = blockIdx.x * 16;
  for (int tt = 0; tt < 16; ++tt) {
    const int t = t0 + tt;
    const size_t qoff = ((size_t)t << 10) + c;
    uint2 dh = *(const uint2*)(qh + qoff);
    uint2 dl = *(const uint2*)(ql + qoff);
    float qv[4];
    qv[0] = b2f((u16)(dh.x & 0xffff)) + b2f((u16)(dl.x & 0xffff));
    qv[1] = b2f((u16)(dh.x >> 16))    + b2f((u16)(dl.x >> 16));
    qv[2] = b2f((u16)(dh.y & 0xffff)) + b2f((u16)(dl.y & 0xffff));
    qv[3] = b2f((u16)(dh.y >> 16))    + b2f((u16)(dl.y >> 16));
#pragma unroll
    for (int i = 0; i < NCAND; ++i) {
      const int sr = (t - lag[i] + LL) & (LL - 1);
      const size_t koff = ((size_t)sr << 10) + c;
      uint2 eh = *(const uint2*)(kh + koff);
      uint2 el = *(const uint2*)(kl + koff);
      float s;
      s  = qv[0] * (b2f((u16)(eh.x & 0xffff)) + b2f((u16)(el.x & 0xffff)));
      s += qv[1] * (b2f((u16)(eh.x >> 16))    + b2f((u16)(el.x >> 16)));
      s += qv[2] * (b2f((u16)(eh.y & 0xffff)) + b2f((u16)(el.y & 0xffff)));
      s += qv[3] * (b2f((u16)(eh.y >> 16))    + b2f((u16)(el.y >> 16)));
      p[i] += s;
    }
  }
#pragma unroll
  for (int i = 0; i < NCAND; ++i) atomicAdd(&part[i], p[i]);
  __syncthreads();
  if (threadIdx.x < NCAND) atomicAdd(&refined[threadIdx.x], part[threadIdx.x]);
}

// pick batch-0 top-7 from refined candidates; softmax weights for all batches
__global__ void finalize_k(const float* __restrict__ cand_val,
                           const int* __restrict__ cand_idx,
                           const float* __restrict__ refined,
                           float* __restrict__ wts, int* __restrict__ ind0)
{
  if (threadIdx.x != 0) return;
  float rv[NCAND]; int ri[NCAND]; bool used[NCAND];
  for (int i = 0; i < NCAND; ++i) {
    rv[i] = refined[i] * (1.f / 1024.f);
    ri[i] = cand_idx[i];
    used[i] = false;
  }
  float v7[NTOP]; int i7[NTOP];
  for (int o = 0; o < NTOP; ++o) {
    int best = -1;
    for (int i = 0; i < NCAND; ++i) {
      if (used[i]) continue;
      if (best < 0 || rv[i] > rv[best] || (rv[i] == rv[best] && ri[i] < ri[best]))
        best = i;
    }
    used[best] = true; v7[o] = rv[best]; i7[o] = ri[best];
  }
  for (int o = 0; o < NTOP; ++o) ind0[o] = i7[o];
  for (int b = 0; b < BB; ++b) {
    float vv[NTOP];
    for (int o = 0; o < NTOP; ++o) vv[o] = (b == 0) ? v7[o] : cand_val[b * NCAND + o];
    float m = vv[0];
    for (int o = 1; o < NTOP; ++o) m = fmaxf(m, vv[o]);
    float e[NTOP], s = 0.f;
    for (int o = 0; o < NTOP; ++o) { e[o] = __expf(vv[o] - m); s += e[o]; }
    for (int o = 0; o < NTOP; ++o) wts[b * NTOP + o] = e[o] / s;
  }
}

// out[b,l,:] = sum_i w[b,i] * v[b,(l+ind0[i]) mod L,:]
__global__ void roll_k(const u16* __restrict__ v, const float* __restrict__ wts,
                       const int* __restrict__ ind0, u16* __restrict__ out)
{
  __shared__ float wsm[NTOP];
  __shared__ int ish[NTOP];
  const size_t idx = (size_t)blockIdx.x * 256 + threadIdx.x;  // 8 bf16 per thread
  const int b = (int)(idx >> 18);          // L*D/8 = 262144
  const int rem = (int)(idx & 262143);
  if (threadIdx.x < NTOP) {
    wsm[threadIdx.x] = wts[b * NTOP + threadIdx.x];
    ish[threadIdx.x] = ind0[threadIdx.x];
  }
  __syncthreads();
  const int l = rem >> 7;
  const int c8 = rem & 127;
  float a[8] = {0.f,0.f,0.f,0.f,0.f,0.f,0.f,0.f};
#pragma unroll
  for (int i = 0; i < NTOP; ++i) {
    const int rowv = (l + ish[i]) & (LL - 1);
    const uint4 d = *(const uint4*)(v + (((size_t)b * LL + rowv) << 10) + (c8 << 3));
    const float wv = wsm[i];
    a[0] += wv * b2f((u16)(d.x & 0xffff)); a[1] += wv * b2f((u16)(d.x >> 16));
    a[2] += wv * b2f((u16)(d.y & 0xffff)); a[3] += wv * b2f((u16)(d.y >> 16));
    a[4] += wv * b2f((u16)(d.z & 0xffff)); a[5] += wv * b2f((u16)(d.z >> 16));
    a[6] += wv * b2f((u16)(d.w & 0xffff)); a[7] += wv * b2f((u16)(d.w >> 16));
  }
  uint4 o;
  o.x = pk2(a[0], a[1]); o.y = pk2(a[2], a[3]);
  o.z = pk2(a[4], a[5]); o.w = pk2(a[6], a[7]);
  *(uint4*)(out + (idx << 3)) = o;
}

// LN(a + b) * g + beta, row length 1024; bf16 a,b; fp32 g,beta.
// fp32_out!=0 -> write fp32 to outf, else bf16 to outb.
__global__ void ln_k(const u16* __restrict__ a, const u16* __restrict__ b,
                     const float* __restrict__ g, const float* __restrict__ be,
                     u16* __restrict__ outb, float* __restrict__ outf,
                     int fp32_out)
{
  const int row = blockIdx.x;
  const int c = threadIdx.x * 4;
  const size_t base = ((size_t)row << 10) + c;
  uint2 da = *(const uint2*)(a + base);
  uint2 db = *(const uint2*)(b + base);
  float xv[4];
  xv[0] = b2f((u16)(da.x & 0xffff)) + b2f((u16)(db.x & 0xffff));
  xv[1] = b2f((u16)(da.x >> 16))    + b2f((u16)(db.x >> 16));
  xv[2] = b2f((u16)(da.y & 0xffff)) + b2f((u16)(db.y & 0xffff));
  xv[3] = b2f((u16)(da.y >> 16))    + b2f((u16)(db.y >> 16));
  float s = xv[0] + xv[1] + xv[2] + xv[3];
  float q = xv[0]*xv[0] + xv[1]*xv[1] + xv[2]*xv[2] + xv[3]*xv[3];
  for (int off = 32; off > 0; off >>= 1) {
    s += __shfl_down(s, off);
    q += __shfl_down(q, off);
  }
  __shared__ float sw[4], sq[4];
  __shared__ float smean, srstd;
  const int w = threadIdx.x >> 6, lane = threadIdx.x & 63;
  if (lane == 0) { sw[w] = s; sq[w] = q; }
  __syncthreads();
  if (threadIdx.x == 0) {
    float S = sw[0] + sw[1] + sw[2] + sw[3];
    float Q = sq[0] + sq[1] + sq[2] + sq[3];
    float m = S * (1.f / 1024.f);
    float var = Q * (1.f / 1024.f) - m * m;
    smean = m; srstd = rsqrtf(var + 1e-6f);
  }
  __syncthreads();
  const float m = smean, rs = srstd;
  const float4 gg = *(const float4*)(g + c);
  const float4 bb = *(const float4*)(be + c);
  float y0 = (xv[0] - m) * rs * gg.x + bb.x;
  float y1 = (xv[1] - m) * rs * gg.y + bb.y;
  float y2 = (xv[2] - m) * rs * gg.z + bb.z;
  float y3 = (xv[3] - m) * rs * gg.w + bb.w;
  if (fp32_out) {
    float4 o; o.x = y0; o.y = y1; o.z = y2; o.w = y3;
    *(float4*)(outf + base) = o;
  } else {
    uint2 o; o.x = pk2(y0, y1); o.y = pk2(y2, y3);
    *(uint2*)(outb + base) = o;
  }
}

// ---------------------------------------------------------------- launcher
extern "C" void kernel_launch(void* const* d_in, const int* in_sizes, int n_in,
                              void* d_out, int out_size, void* d_ws, size_t ws_size,
                              hipStream_t stream)
{
  const float* x   = (const float*)d_in[0];
  const float* Wq  = (const float*)d_in[1];
  const float* bq  = (const float*)d_in[2];
  const float* Wk  = (const float*)d_in[3];
  const float* bk  = (const float*)d_in[4];
  const float* Wv  = (const float*)d_in[5];
  const float* bv  = (const float*)d_in[6];
  const float* Wo  = (const float*)d_in[7];
  const float* bo  = (const float*)d_in[8];
  const float* g1  = (const float*)d_in[9];
  const float* be1 = (const float*)d_in[10];
  const float* c1w = (const float*)d_in[11];
  const float* c1b = (const float*)d_in[12];
  const float* c2w = (const float*)d_in[13];
  const float* c2b = (const float*)d_in[14];
  const float* g2  = (const float*)d_in[15];
  const float* be2 = (const float*)d_in[16];

  // workspace layout (bytes); peak requirement 0xA100000 = 161.5 MiB
  char* ws = (char*)d_ws;
  if (ws_size < 0xA100000ull) return;  // insufficient scratch -> clean fail
  u16* WqT  = (u16*)(ws + 0x0000000);  // 2 MiB each (bf16 1024x1024)
  u16* WkT  = (u16*)(ws + 0x0200000);
  u16* WvT  = (u16*)(ws + 0x0400000);
  u16* WoT  = (u16*)(ws + 0x0600000);
  u16* C1T  = (u16*)(ws + 0x0800000);  // 8 MiB (4096x1024)
  u16* C2T  = (u16*)(ws + 0x1000000);  // 8 MiB (1024x4096)
  u16* Xb   = (u16*)(ws + 0x1800000);  // 32 MiB (16384x1024 bf16 of x)
  u16* Qb   = (u16*)(ws + 0x3800000);  // 32 MiB
  u16* Kb   = (u16*)(ws + 0x5800000);  // 32 MiB
  u16* Vb   = (u16*)(ws + 0x7800000);  // 32 MiB
  u16* Qlo  = (u16*)(ws + 0x9800000);  // 4 MiB (batch 0 residual)
  u16* Klo  = (u16*)(ws + 0x9C00000);  // 4 MiB
  float* Rbuf = (float*)(ws + 0xA000000);  // 64 KiB (8x2048 lag scores)
  float* REF  = (float*)(ws + 0xA010000);  // 16 floats (contiguous after Rbuf)
  float* CV   = (float*)(ws + 0xA010100);
  int*   CI   = (int*)  (ws + 0xA010300);
  float* WTS  = (float*)(ws + 0xA010500);
  int*   IND0 = (int*)  (ws + 0xA010600);
  // reuse map (lifetimes audited):
  u16* ROLL = Qb;                        // q dead after refine
  u16* ATTN = Kb;                        // k dead after refine
  u16* X1   = Vb;                        // v dead after roll
  u16* Yb   = Xb;                        // 64 MiB FFN hidden (Xb+Qb, both dead)
  u16* Zb   = Kb;                        // 32 MiB FFN out (ATTN dead after ln1)

  const dim3 tb(32, 8);
  // fused fp32->bf16 weight transposes to (N,K) for the B^T GEMM pattern
  transpose_k<<<dim3(32, 32),  tb, 0, stream>>>(Wq,  WqT, 1024, 1024);
  transpose_k<<<dim3(32, 32),  tb, 0, stream>>>(Wk,  WkT, 1024, 1024);
  transpose_k<<<dim3(32, 32),  tb, 0, stream>>>(Wv,  WvT, 1024, 1024);
  transpose_k<<<dim3(32, 32),  tb, 0, stream>>>(Wo,  WoT, 1024, 1024);
  transpose_k<<<dim3(128, 32), tb, 0, stream>>>(c1w, C1T, 1024, 4096);
  transpose_k<<<dim3(32, 128), tb, 0, stream>>>(c2w, C2T, 4096, 1024);

  convert_k<<<8192, 256, 0, stream>>>(x, Xb, NT * DD / 8);
  zero_k<<<65, 256, 0, stream>>>(Rbuf, 16384 + 16);  // Rbuf + REF contiguous

  // q,k,v projections (q,k also store batch-0 lo residual for refine)
  gemm_bias_k<<<dim3(8, 128), 256, 0, stream>>>(Xb, WqT, bq, Qb, Qlo,
      NT, DD, DD, DD, DD, DD, 0, LL);
  gemm_bias_k<<<dim3(8, 128), 256, 0, stream>>>(Xb, WkT, bk, Kb, Klo,
      NT, DD, DD, DD, DD, DD, 0, LL);
  gemm_bias_k<<<dim3(8, 128), 256, 0, stream>>>(Xb, WvT, bv, Vb, (u16*)nullptr,
      NT, DD, DD, DD, DD, DD, 0, 0);

  // autocorrelation lag scores via gram + fused diagonal reduce
  gram_k<<<dim3(16, 16, 8), 256, 0, stream>>>(Qb, Kb, Rbuf);
  topk16_k<<<8, 256, 0, stream>>>(Rbuf, CV, CI);
  refine_k<<<128, 256, 0, stream>>>(Qb, Qlo, Kb, Klo, CI, REF);
  finalize_k<<<1, 64, 0, stream>>>(CV, CI, REF, WTS, IND0);

  // weighted roll aggregation, then output projection
  roll_k<<<8192, 256, 0, stream>>>(Vb, WTS, IND0, ROLL);
  gemm_bias_k<<<dim3(8, 128), 256, 0, stream>>>(ROLL, WoT, bo, ATTN, (u16*)nullptr,
      NT, DD, DD, DD, DD, DD, 0, 0);
  ln_k<<<NT, 256, 0, stream>>>(Xb, ATTN, g1, be1, X1, (float*)nullptr, 0);

  // FFN in 2 row-chunks of 8192 (bounds hidden scratch to 64 MiB)
  for (int cc = 0; cc < 2; ++cc) {
    const u16* xa = X1 + (size_t)cc * 8192 * DD;
    u16* za = Zb + (size_t)cc * 8192 * DD;
    gemm_bias_k<<<dim3(32, 64), 256, 0, stream>>>(xa, C1T, c1b, Yb, (u16*)nullptr,
        8192, FF, DD, DD, DD, FF, 1, 0);
    gemm_bias_k<<<dim3(8, 64), 256, 0, stream>>>(Yb, C2T, c2b, za, (u16*)nullptr,
        8192, DD, FF, FF, FF, DD, 0, 0);
  }
  ln_k<<<NT, 256, 0, stream>>>(X1, Zb, g2, be2, (u16*)nullptr, (float*)d_out, 1);
}

// Round 5
// 1020.418 us; speedup vs baseline: 1.0748x; 1.0748x over previous
//
#include <hip/hip_runtime.h>
#include <cstdint>
#include <cstddef>

// EncoderLayer (Autoformer auto-correlation) on gfx950. fp32 I/O, bf16 MFMA.
// R5: BK 32 -> 64 with split-half staging ([2][128][32] sub-tiles). Fixes the
// 2.3x L2-line over-fetch (BK=32 used 64B of each 128B line; FETCH_SIZE=147MB
// vs 64MB input on gram) and halves the per-K-step vmcnt(0)+barrier drains
// (32 MFMAs/wave per drain instead of 16). Layout keeps 64-B rows so the
// wave-uniform global_load_lds mapping and conflict-light ds_reads survive.
//
// Key identity: mean over channels of irfft(rfft(q)*conj(rfft(k))) ==
//   (1/D) * wrap-diagonal sums of the per-batch gram matrix q @ k^T.

typedef unsigned short u16;
typedef unsigned int   u32;
typedef __bf16  bf16x8 __attribute__((ext_vector_type(8)));
typedef float   f32x4  __attribute__((ext_vector_type(4)));

#define BB 8
#define LL 2048
#define DD 1024
#define FF 4096
#define NT 16384   // B*L
#define NCAND 16
#define NTOP 7
#define HALF 4096  // u16 elems per 128x32 sub-tile

static __device__ __forceinline__ float b2f(u16 u) {
  union { u32 i; float f; } x; x.i = ((u32)u) << 16; return x.f;
}
static __device__ __forceinline__ u16 f2b(float f) {
  union { float f; u32 i; } x; x.f = f;
  u32 r = (x.i + 0x7fffu + ((x.i >> 16) & 1u)) >> 16;  // RNE
  return (u16)r;
}
static __device__ __forceinline__ u32 pk2(float a, float b) {
  return (u32)f2b(a) | ((u32)f2b(b) << 16);
}

// async global->LDS, 16B per lane; LDS dest = wave-uniform base + lane*16
#define GLD_LDS16(gp, lp) __builtin_amdgcn_global_load_lds( \
    (const __attribute__((address_space(1))) u32*)(void*)(gp), \
    (__attribute__((address_space(3))) u32*)(void*)(lp), 16, 0, 0)

// ---------------------------------------------------------------- GEMM core
// C(MxN) = A(MxK) @ Bt(NxK)^T, bf16 in, fp32 accum. 128x128 tile, BK=64
// as two 32-col sub-tiles; 256 threads = 4 waves, each wave 64x64 via 4x4
// of mfma_f32_16x16x32_bf16, 2 k-sub-steps per barrier pair.
__device__ __forceinline__ void gemm_tile(
    const u16* __restrict__ A, const u16* __restrict__ Bt,
    int lda, int ldb, int K, u16* As, u16* Bs, f32x4 acc[4][4])
{
  const int tid  = threadIdx.x;
  const int w    = tid >> 6;
  const int lane = tid & 63;
  const bool isA = (w < 2);
  const u16* G   = isA ? A : Bt;
  const int ldg  = isA ? lda : ldb;
  u16* S         = isA ? As : Bs;
  const int rbase = (w & 1) * 64;            // 64-row staging slice per wave
  const int srow  = rbase + (lane >> 2);
  const int scol  = (lane & 3) * 8;
  const int wm = (w >> 1) * 64;              // wave tile origin
  const int wn = (w & 1) * 64;
  const int fm = lane & 15;                  // A/B fragment row (m or n)
  const int fk = (lane >> 4) * 8;            // fragment k offset (0..31 range)
  const u16* gbase = G + (size_t)srow * ldg + scol;

  for (int kk = 0; kk < K; kk += 64) {
    // stage both 32-col halves; the two issues per row-group are adjacent
    // halves of the same 128-B lines -> full line utilization
#pragma unroll
    for (int j = 0; j < 4; ++j) {
      GLD_LDS16(gbase + (size_t)(j * 16) * ldg + kk,
                S + (rbase + j * 16) * 32);
      GLD_LDS16(gbase + (size_t)(j * 16) * ldg + kk + 32,
                S + HALF + (rbase + j * 16) * 32);
    }
    __syncthreads();   // drains vmcnt -> both sub-tiles ready
#pragma unroll
    for (int sub = 0; sub < 2; ++sub) {
      const u16* as = As + sub * HALF;
      const u16* bs = Bs + sub * HALF;
      bf16x8 af[4], bfv[4];
#pragma unroll
      for (int i = 0; i < 4; ++i)
        af[i] = *(const bf16x8*)(as + (wm + i * 16 + fm) * 32 + fk);
#pragma unroll
      for (int j = 0; j < 4; ++j)
        bfv[j] = *(const bf16x8*)(bs + (wn + j * 16 + fm) * 32 + fk);
#pragma unroll
      for (int i = 0; i < 4; ++i)
#pragma unroll
        for (int j = 0; j < 4; ++j)
          acc[i][j] = __builtin_amdgcn_mfma_f32_16x16x32_bf16(af[i], bfv[j], acc[i][j], 0, 0, 0);
    }
    __syncthreads();   // LDS readers done before next iter's DMA writes
  }
}

// C = A@Bt^T + bias(fp32), optional relu; optional bf16 "lo" residual store
// for rows < lo_rows (double-bf16 split used by the refine kernel).
__global__ __launch_bounds__(256, 2)
void gemm_bias_k(const u16* __restrict__ A, const u16* __restrict__ Bt,
                 const float* __restrict__ bias, u16* __restrict__ C,
                 u16* __restrict__ Clo, int M, int N, int K,
                 int lda, int ldb, int ldc, int relu, int lo_rows)
{
  __shared__ u16 As[2 * HALF];
  __shared__ u16 Bs[2 * HALF];
  f32x4 acc[4][4];
#pragma unroll
  for (int i = 0; i < 4; ++i)
#pragma unroll
    for (int j = 0; j < 4; ++j)
#pragma unroll
      for (int r = 0; r < 4; ++r) acc[i][j][r] = 0.f;

  const int bm = blockIdx.y * 128, bn = blockIdx.x * 128;
  gemm_tile(A + (size_t)bm * lda, Bt + (size_t)bn * ldb, lda, ldb, K, As, Bs, acc);

  const int tid = threadIdx.x, w = tid >> 6, lane = tid & 63;
  const int wm = (w >> 1) * 64, wn = (w & 1) * 64;
  const int crow = (lane >> 4) * 4, ccol = lane & 15;
  float bvs[4];
#pragma unroll
  for (int j = 0; j < 4; ++j) bvs[j] = bias[bn + wn + j * 16 + ccol];
#pragma unroll
  for (int i = 0; i < 4; ++i) {
#pragma unroll
    for (int r = 0; r < 4; ++r) {
      const int row = bm + wm + i * 16 + crow + r;
      const size_t rowoff = (size_t)row * ldc;
#pragma unroll
      for (int j = 0; j < 4; ++j) {
        float val = acc[i][j][r] + bvs[j];
        if (relu) val = fmaxf(val, 0.f);
        const int col = bn + wn + j * 16 + ccol;
        const u16 hb = f2b(val);
        C[rowoff + col] = hb;
        if (Clo != nullptr && row < lo_rows)
          Clo[rowoff + col] = f2b(val - b2f(hb));
      }
    }
  }
}

// Gram GEMM with fused wrap-diagonal reduction:
// r[b,l] += sum over tile elems of q[t,:]*k[s,:] where (t-s) mod L == l
__global__ __launch_bounds__(256, 2)
void gram_k(const u16* __restrict__ q, const u16* __restrict__ kmat,
            float* __restrict__ rout)
{
  __shared__ u16 As[2 * HALF];
  __shared__ u16 Bs[2 * HALF];
  __shared__ float diag[255];
  const int b = blockIdx.z;
  const int bm = blockIdx.y * 128, bn = blockIdx.x * 128;
  for (int idx = threadIdx.x; idx < 255; idx += 256) diag[idx] = 0.f;

  f32x4 acc[4][4];
#pragma unroll
  for (int i = 0; i < 4; ++i)
#pragma unroll
    for (int j = 0; j < 4; ++j)
#pragma unroll
      for (int r = 0; r < 4; ++r) acc[i][j][r] = 0.f;

  const u16* A  = q    + (size_t)b * LL * DD + (size_t)bm * DD;
  const u16* Bt = kmat + (size_t)b * LL * DD + (size_t)bn * DD;
  gemm_tile(A, Bt, DD, DD, DD, As, Bs, acc);

  __syncthreads();   // diag[] zero-init visible; LDS readers done
  const int tid = threadIdx.x, w = tid >> 6, lane = tid & 63;
  const int wm = (w >> 1) * 64, wn = (w & 1) * 64;
  const int crow = (lane >> 4) * 4, ccol = lane & 15;
  const int dbase = wm - wn + crow - ccol + 127;
#pragma unroll
  for (int d = -3; d <= 3; ++d) {
#pragma unroll
    for (int r = 0; r < 4; ++r) {
      float s = 0.f;
#pragma unroll
      for (int i = 0; i < 4; ++i) {
        const int j = i - d;
        if (0 <= j && j < 4) s += acc[i][j][r];
      }
      atomicAdd(&diag[dbase + d * 16 + r], s);
    }
  }
  __syncthreads();
  for (int idx = threadIdx.x; idx < 255; idx += 256) {
    const int l = ((bm - bn + idx - 127) + 4096) & (LL - 1);
    atomicAdd(&rout[b * LL + l], diag[idx]);
  }
}

// ----------------------------------------------------------- small kernels
__global__ void zero_k(float* p, int n) {
  int i = blockIdx.x * 256 + threadIdx.x;
  if (i < n) p[i] = 0.f;
}

// fp32 -> bf16, 8 elements per thread
__global__ void convert_k(const float* __restrict__ in, u16* __restrict__ out,
                          int n8)
{
  const int i = blockIdx.x * 256 + threadIdx.x;
  if (i >= n8) return;
  const float4 f0 = *(const float4*)(in + (size_t)i * 8);
  const float4 f1 = *(const float4*)(in + (size_t)i * 8 + 4);
  uint4 o;
  o.x = pk2(f0.x, f0.y); o.y = pk2(f0.z, f0.w);
  o.z = pk2(f1.x, f1.y); o.w = pk2(f1.z, f1.w);
  *(uint4*)(out + (size_t)i * 8) = o;
}

// fp32 in (R x C) -> bf16 transposed out (C x R)
__global__ void transpose_k(const float* __restrict__ in, u16* __restrict__ out,
                            int R, int C)
{
  __shared__ float tile[32][33];
  const int bx = blockIdx.x * 32;  // col base
  const int by = blockIdx.y * 32;  // row base
  const int tx = threadIdx.x, ty = threadIdx.y;
#pragma unroll
  for (int i = 0; i < 32; i += 8)
    tile[ty + i][tx] = in[(size_t)(by + ty + i) * C + bx + tx];
  __syncthreads();
#pragma unroll
  for (int i = 0; i < 32; i += 8)
    out[(size_t)(bx + ty + i) * R + by + tx] = f2b(tile[tx][ty + i]);
}

// per-batch iterative top-16 argmax (stable: ties -> lower index, like lax.top_k)
__global__ void topk16_k(const float* __restrict__ r, float* __restrict__ cand_val,
                         int* __restrict__ cand_idx)
{
  const int b = blockIdx.x;
  __shared__ float vals[LL];
  __shared__ float bvv[256];
  __shared__ int   bii[256];
  for (int i = threadIdx.x; i < LL; i += 256) vals[i] = r[b * LL + i] * (1.f / 1024.f);
  __syncthreads();
  for (int it = 0; it < NCAND; ++it) {
    float best = -1e30f; int bidx = 0;
    for (int i = threadIdx.x; i < LL; i += 256) {
      float v = vals[i];
      if (v > best) { best = v; bidx = i; }
    }
    bvv[threadIdx.x] = best; bii[threadIdx.x] = bidx;
    __syncthreads();
    for (int s = 128; s > 0; s >>= 1) {
      if ((int)threadIdx.x < s) {
        float ov = bvv[threadIdx.x + s]; int oi = bii[threadIdx.x + s];
        if (ov > bvv[threadIdx.x] ||
            (ov == bvv[threadIdx.x] && oi < bii[threadIdx.x])) {
          bvv[threadIdx.x] = ov; bii[threadIdx.x] = oi;
        }
      }
      __syncthreads();
    }
    if (threadIdx.x == 0) {
      cand_val[b * NCAND + it] = bvv[0];
      cand_idx[b * NCAND + it] = bii[0];
      vals[bii[0]] = -1e30f;
    }
    __syncthreads();
  }
}

// high-precision rescore of batch-0's 16 candidate lags using hi+lo splits
__global__ void refine_k(const u16* __restrict__ qh, const u16* __restrict__ ql,
                         const u16* __restrict__ kh, const u16* __restrict__ kl,
                         const int* __restrict__ ci, float* __restrict__ refined)
{
  __shared__ int lag[NCAND];
  __shared__ float part[NCAND];
  if (threadIdx.x < NCAND) { lag[threadIdx.x] = ci[threadIdx.x]; part[threadIdx.x] = 0.f; }
  __syncthreads();
  const int c = threadIdx.x * 4;
  float p[NCAND];
#pragma unroll
  for (int i = 0; i < NCAND; ++i) p[i] = 0.f;
  const int t0 = blockIdx.x * 16;
  for (int tt = 0; tt < 16; ++tt) {
    const int t = t0 + tt;
    const size_t qoff = ((size_t)t << 10) + c;
    uint2 dh = *(const uint2*)(qh + qoff);
    uint2 dl = *(const uint2*)(ql + qoff);
    float qv[4];
    qv[0] = b2f((u16)(dh.x & 0xffff)) + b2f((u16)(dl.x & 0xffff));
    qv[1] = b2f((u16)(dh.x >> 16))    + b2f((u16)(dl.x >> 16));
    qv[2] = b2f((u16)(dh.y & 0xffff)) + b2f((u16)(dl.y & 0xffff));
    qv[3] = b2f((u16)(dh.y >> 16))    + b2f((u16)(dl.y >> 16));
#pragma unroll
    for (int i = 0; i < NCAND; ++i) {
      const int sr = (t - lag[i] + LL) & (LL - 1);
      const size_t koff = ((size_t)sr << 10) + c;
      uint2 eh = *(const uint2*)(kh + koff);
      uint2 el = *(const uint2*)(kl + koff);
      float s;
      s  = qv[0] * (b2f((u16)(eh.x & 0xffff)) + b2f((u16)(el.x & 0xffff)));
      s += qv[1] * (b2f((u16)(eh.x >> 16))    + b2f((u16)(el.x >> 16)));
      s += qv[2] * (b2f((u16)(eh.y & 0xffff)) + b2f((u16)(el.y & 0xffff)));
      s += qv[3] * (b2f((u16)(eh.y >> 16))    + b2f((u16)(el.y >> 16)));
      p[i] += s;
    }
  }
#pragma unroll
  for (int i = 0; i < NCAND; ++i) atomicAdd(&part[i], p[i]);
  __syncthreads();
  if (threadIdx.x < NCAND) atomicAdd(&refined[threadIdx.x], part[threadIdx.x]);
}

// pick batch-0 top-7 from refined candidates; softmax weights for all batches
__global__ void finalize_k(const float* __restrict__ cand_val,
                           const int* __restrict__ cand_idx,
                           const float* __restrict__ refined,
                           float* __restrict__ wts, int* __restrict__ ind0)
{
  if (threadIdx.x != 0) return;
  float rv[NCAND]; int ri[NCAND]; bool used[NCAND];
  for (int i = 0; i < NCAND; ++i) {
    rv[i] = refined[i] * (1.f / 1024.f);
    ri[i] = cand_idx[i];
    used[i] = false;
  }
  float v7[NTOP]; int i7[NTOP];
  for (int o = 0; o < NTOP; ++o) {
    int best = -1;
    for (int i = 0; i < NCAND; ++i) {
      if (used[i]) continue;
      if (best < 0 || rv[i] > rv[best] || (rv[i] == rv[best] && ri[i] < ri[best]))
        best = i;
    }
    used[best] = true; v7[o] = rv[best]; i7[o] = ri[best];
  }
  for (int o = 0; o < NTOP; ++o) ind0[o] = i7[o];
  for (int b = 0; b < BB; ++b) {
    float vv[NTOP];
    for (int o = 0; o < NTOP; ++o) vv[o] = (b == 0) ? v7[o] : cand_val[b * NCAND + o];
    float m = vv[0];
    for (int o = 1; o < NTOP; ++o) m = fmaxf(m, vv[o]);
    float e[NTOP], s = 0.f;
    for (int o = 0; o < NTOP; ++o) { e[o] = __expf(vv[o] - m); s += e[o]; }
    for (int o = 0; o < NTOP; ++o) wts[b * NTOP + o] = e[o] / s;
  }
}

// out[b,l,:] = sum_i w[b,i] * v[b,(l+ind0[i]) mod L,:]
__global__ void roll_k(const u16* __restrict__ v, const float* __restrict__ wts,
                       const int* __restrict__ ind0, u16* __restrict__ out)
{
  __shared__ float wsm[NTOP];
  __shared__ int ish[NTOP];
  const size_t idx = (size_t)blockIdx.x * 256 + threadIdx.x;  // 8 bf16 per thread
  const int b = (int)(idx >> 18);          // L*D/8 = 262144
  const int rem = (int)(idx & 262143);
  if (threadIdx.x < NTOP) {
    wsm[threadIdx.x] = wts[b * NTOP + threadIdx.x];
    ish[threadIdx.x] = ind0[threadIdx.x];
  }
  __syncthreads();
  const int l = rem >> 7;
  const int c8 = rem & 127;
  float a[8] = {0.f,0.f,0.f,0.f,0.f,0.f,0.f,0.f};
#pragma unroll
  for (int i = 0; i < NTOP; ++i) {
    const int rowv = (l + ish[i]) & (LL - 1);
    const uint4 d = *(const uint4*)(v + (((size_t)b * LL + rowv) << 10) + (c8 << 3));
    const float wv = wsm[i];
    a[0] += wv * b2f((u16)(d.x & 0xffff)); a[1] += wv * b2f((u16)(d.x >> 16));
    a[2] += wv * b2f((u16)(d.y & 0xffff)); a[3] += wv * b2f((u16)(d.y >> 16));
    a[4] += wv * b2f((u16)(d.z & 0xffff)); a[5] += wv * b2f((u16)(d.z >> 16));
    a[6] += wv * b2f((u16)(d.w & 0xffff)); a[7] += wv * b2f((u16)(d.w >> 16));
  }
  uint4 o;
  o.x = pk2(a[0], a[1]); o.y = pk2(a[2], a[3]);
  o.z = pk2(a[4], a[5]); o.w = pk2(a[6], a[7]);
  *(uint4*)(out + (idx << 3)) = o;
}

// LN(a + b) * g + beta, row length 1024; bf16 a,b; fp32 g,beta.
// fp32_out!=0 -> write fp32 to outf, else bf16 to outb.
__global__ void ln_k(const u16* __restrict__ a, const u16* __restrict__ b,
                     const float* __restrict__ g, const float* __restrict__ be,
                     u16* __restrict__ outb, float* __restrict__ outf,
                     int fp32_out)
{
  const int row = blockIdx.x;
  const int c = threadIdx.x * 4;
  const size_t base = ((size_t)row << 10) + c;
  uint2 da = *(const uint2*)(a + base);
  uint2 db = *(const uint2*)(b + base);
  float xv[4];
  xv[0] = b2f((u16)(da.x & 0xffff)) + b2f((u16)(db.x & 0xffff));
  xv[1] = b2f((u16)(da.x >> 16))    + b2f((u16)(db.x >> 16));
  xv[2] = b2f((u16)(da.y & 0xffff)) + b2f((u16)(db.y & 0xffff));
  xv[3] = b2f((u16)(da.y >> 16))    + b2f((u16)(db.y >> 16));
  float s = xv[0] + xv[1] + xv[2] + xv[3];
  float q = xv[0]*xv[0] + xv[1]*xv[1] + xv[2]*xv[2] + xv[3]*xv[3];
  for (int off = 32; off > 0; off >>= 1) {
    s += __shfl_down(s, off);
    q += __shfl_down(q, off);
  }
  __shared__ float sw[4], sq[4];
  __shared__ float smean, srstd;
  const int w = threadIdx.x >> 6, lane = threadIdx.x & 63;
  if (lane == 0) { sw[w] = s; sq[w] = q; }
  __syncthreads();
  if (threadIdx.x == 0) {
    float S = sw[0] + sw[1] + sw[2] + sw[3];
    float Q = sq[0] + sq[1] + sq[2] + sq[3];
    float m = S * (1.f / 1024.f);
    float var = Q * (1.f / 1024.f) - m * m;
    smean = m; srstd = rsqrtf(var + 1e-6f);
  }
  __syncthreads();
  const float m = smean, rs = srstd;
  const float4 gg = *(const float4*)(g + c);
  const float4 bb = *(const float4*)(be + c);
  float y0 = (xv[0] - m) * rs * gg.x + bb.x;
  float y1 = (xv[1] - m) * rs * gg.y + bb.y;
  float y2 = (xv[2] - m) * rs * gg.z + bb.z;
  float y3 = (xv[3] - m) * rs * gg.w + bb.w;
  if (fp32_out) {
    float4 o; o.x = y0; o.y = y1; o.z = y2; o.w = y3;
    *(float4*)(outf + base) = o;
  } else {
    uint2 o; o.x = pk2(y0, y1); o.y = pk2(y2, y3);
    *(uint2*)(outb + base) = o;
  }
}

// ---------------------------------------------------------------- launcher
extern "C" void kernel_launch(void* const* d_in, const int* in_sizes, int n_in,
                              void* d_out, int out_size, void* d_ws, size_t ws_size,
                              hipStream_t stream)
{
  const float* x   = (const float*)d_in[0];
  const float* Wq  = (const float*)d_in[1];
  const float* bq  = (const float*)d_in[2];
  const float* Wk  = (const float*)d_in[3];
  const float* bk  = (const float*)d_in[4];
  const float* Wv  = (const float*)d_in[5];
  const float* bv  = (const float*)d_in[6];
  const float* Wo  = (const float*)d_in[7];
  const float* bo  = (const float*)d_in[8];
  const float* g1  = (const float*)d_in[9];
  const float* be1 = (const float*)d_in[10];
  const float* c1w = (const float*)d_in[11];
  const float* c1b = (const float*)d_in[12];
  const float* c2w = (const float*)d_in[13];
  const float* c2b = (const float*)d_in[14];
  const float* g2  = (const float*)d_in[15];
  const float* be2 = (const float*)d_in[16];

  // workspace layout (bytes); peak requirement 0xA100000 = 161.5 MiB
  char* ws = (char*)d_ws;
  if (ws_size < 0xA100000ull) return;  // insufficient scratch -> clean fail
  u16* WqT  = (u16*)(ws + 0x0000000);  // 2 MiB each (bf16 1024x1024)
  u16* WkT  = (u16*)(ws + 0x0200000);
  u16* WvT  = (u16*)(ws + 0x0400000);
  u16* WoT  = (u16*)(ws + 0x0600000);
  u16* C1T  = (u16*)(ws + 0x0800000);  // 8 MiB (4096x1024)
  u16* C2T  = (u16*)(ws + 0x1000000);  // 8 MiB (1024x4096)
  u16* Xb   = (u16*)(ws + 0x1800000);  // 32 MiB (16384x1024 bf16 of x)
  u16* Qb   = (u16*)(ws + 0x3800000);  // 32 MiB
  u16* Kb   = (u16*)(ws + 0x5800000);  // 32 MiB
  u16* Vb   = (u16*)(ws + 0x7800000);  // 32 MiB
  u16* Qlo  = (u16*)(ws + 0x9800000);  // 4 MiB (batch 0 residual)
  u16* Klo  = (u16*)(ws + 0x9C00000);  // 4 MiB
  float* Rbuf = (float*)(ws + 0xA000000);  // 64 KiB (8x2048 lag scores)
  float* REF  = (float*)(ws + 0xA010000);  // 16 floats (contiguous after Rbuf)
  float* CV   = (float*)(ws + 0xA010100);
  int*   CI   = (int*)  (ws + 0xA010300);
  float* WTS  = (float*)(ws + 0xA010500);
  int*   IND0 = (int*)  (ws + 0xA010600);
  // reuse map (lifetimes audited):
  u16* ROLL = Qb;                        // q dead after refine
  u16* ATTN = Kb;                        // k dead after refine
  u16* X1   = Vb;                        // v dead after roll
  u16* Yb   = Xb;                        // 64 MiB FFN hidden (Xb+Qb, both dead)
  u16* Zb   = Kb;                        // 32 MiB FFN out (ATTN dead after ln1)

  const dim3 tb(32, 8);
  // fused fp32->bf16 weight transposes to (N,K) for the B^T GEMM pattern
  transpose_k<<<dim3(32, 32),  tb, 0, stream>>>(Wq,  WqT, 1024, 1024);
  transpose_k<<<dim3(32, 32),  tb, 0, stream>>>(Wk,  WkT, 1024, 1024);
  transpose_k<<<dim3(32, 32),  tb, 0, stream>>>(Wv,  WvT, 1024, 1024);
  transpose_k<<<dim3(32, 32),  tb, 0, stream>>>(Wo,  WoT, 1024, 1024);
  transpose_k<<<dim3(128, 32), tb, 0, stream>>>(c1w, C1T, 1024, 4096);
  transpose_k<<<dim3(32, 128), tb, 0, stream>>>(c2w, C2T, 4096, 1024);

  convert_k<<<8192, 256, 0, stream>>>(x, Xb, NT * DD / 8);
  zero_k<<<65, 256, 0, stream>>>(Rbuf, 16384 + 16);  // Rbuf + REF contiguous

  // q,k,v projections (q,k also store batch-0 lo residual for refine)
  gemm_bias_k<<<dim3(8, 128), 256, 0, stream>>>(Xb, WqT, bq, Qb, Qlo,
      NT, DD, DD, DD, DD, DD, 0, LL);
  gemm_bias_k<<<dim3(8, 128), 256, 0, stream>>>(Xb, WkT, bk, Kb, Klo,
      NT, DD, DD, DD, DD, DD, 0, LL);
  gemm_bias_k<<<dim3(8, 128), 256, 0, stream>>>(Xb, WvT, bv, Vb, (u16*)nullptr,
      NT, DD, DD, DD, DD, DD, 0, 0);

  // autocorrelation lag scores via gram + fused diagonal reduce
  gram_k<<<dim3(16, 16, 8), 256, 0, stream>>>(Qb, Kb, Rbuf);
  topk16_k<<<8, 256, 0, stream>>>(Rbuf, CV, CI);
  refine_k<<<128, 256, 0, stream>>>(Qb, Qlo, Kb, Klo, CI, REF);
  finalize_k<<<1, 64, 0, stream>>>(CV, CI, REF, WTS, IND0);

  // weighted roll aggregation, then output projection
  roll_k<<<8192, 256, 0, stream>>>(Vb, WTS, IND0, ROLL);
  gemm_bias_k<<<dim3(8, 128), 256, 0, stream>>>(ROLL, WoT, bo, ATTN, (u16*)nullptr,
      NT, DD, DD, DD, DD, DD, 0, 0);
  ln_k<<<NT, 256, 0, stream>>>(Xb, ATTN, g1, be1, X1, (float*)nullptr, 0);

  // FFN in 2 row-chunks of 8192 (bounds hidden scratch to 64 MiB)
  for (int cc = 0; cc < 2; ++cc) {
    const u16* xa = X1 + (size_t)cc * 8192 * DD;
    u16* za = Zb + (size_t)cc * 8192 * DD;
    gemm_bias_k<<<dim3(32, 64), 256, 0, stream>>>(xa, C1T, c1b, Yb, (u16*)nullptr,
        8192, FF, DD, DD, DD, FF, 1, 0);
    gemm_bias_k<<<dim3(8, 64), 256, 0, stream>>>(Yb, C2T, c2b, za, (u16*)nullptr,
        8192, DD, FF, FF, FF, DD, 0, 0);
  }
  ln_k<<<NT, 256, 0, stream>>>(X1, Zb, g2, be2, (u16*)nullptr, (float*)d_out, 1);
}